// Round 10
// baseline (707.827 us; speedup 1.0000x reference)
//
#include <hip/hip_runtime.h>

typedef __bf16 bf16x8 __attribute__((ext_vector_type(8)));
typedef float  f32x4  __attribute__((ext_vector_type(4)));

#define LOG2E 1.4426950408889634f

static __device__ __forceinline__ float fexp2(float x) { return __builtin_amdgcn_exp2f(x); }
static __device__ __forceinline__ float frcp(float x)  { return __builtin_amdgcn_rcpf(x); }
static __device__ __forceinline__ float fsigmoid(float x) { return frcp(1.0f + fexp2(-LOG2E * x)); }
static __device__ __forceinline__ float ftanh(float x)    { return 2.0f * frcp(1.0f + fexp2(-2.0f * LOG2E * x)) - 1.0f; }

// ---------------------------------------------------------------------------
// Prep: pack 4 [512x512] fp32 weights into bf16 16x16x32-B-fragment order,
// GATE-CONTIGUOUS: Wp[(((cn*16+ks)*4+g)*64 + lt)*8 + e]
//   = W_g[cn*16+(lt&15)][ks*32+(lt>>4)*8+e]
// -> per (cn,ks) the 4 gates' 1-KB fragments are contiguous (4 KB): one base
//    pointer + immediate offsets 0/1024/2048/3072 B, coalesced 1 KB each.
// ---------------------------------------------------------------------------
__global__ __launch_bounds__(256) void wpack(const float* __restrict__ Wf,
                                             const float* __restrict__ Wi,
                                             const float* __restrict__ Wg,
                                             const float* __restrict__ Wo,
                                             __bf16* __restrict__ Wp)
{
    int idx = blockIdx.x * 256 + threadIdx.x;      // [0, 131072)
    int kg  = idx & 63;                            // k-group of 8
    int j   = (idx >> 6) & 511;                    // weight row = output col
    int g   = idx >> 15;
    const float* src = (g == 0) ? Wf : (g == 1) ? Wi : (g == 2) ? Wg : Wo;
    const float4* s4 = (const float4*)(src + j * 512 + kg * 8);
    float4 v0 = s4[0], v1 = s4[1];
    bf16x8 o;
    o[0] = (__bf16)v0.x; o[1] = (__bf16)v0.y; o[2] = (__bf16)v0.z; o[3] = (__bf16)v0.w;
    o[4] = (__bf16)v1.x; o[5] = (__bf16)v1.y; o[6] = (__bf16)v1.z; o[7] = (__bf16)v1.w;
    int cn = j >> 4;                               // 16-col group
    int ks = kg >> 2;                              // K=32 step
    int lt = (j & 15) + (kg & 3) * 16;             // lane slot
    size_t dst = ((size_t)(((cn * 16 + ks) * 4 + g) * 64 + lt)) * 8;
    *(bf16x8*)(Wp + dst) = o;
}

// ---------------------------------------------------------------------------
// Main fused kernel (round-6 structure + explicit 2-deep B pipeline).
// Block: 512 thr (8 waves), BM=128 rows, 128 KiB LDS, 1 block/CU.
// Each wave owns ALL 128 rows x 16 cols x 4 gates: acc = 8m x 4g x 4 = 128 AGPR.
// K-loop: B(ks+1) issued before MFMA(ks) into the alternate register set, so
// 4-8 L2 loads stay in flight under each 620-cycle MFMA batch.
// ---------------------------------------------------------------------------
__global__ __launch_bounds__(512, 2) void lstm_main(
    const float* __restrict__ xin, const float* __restrict__ stm,
    const __bf16* __restrict__ Wp,
    const float* __restrict__ bfv, const float* __restrict__ biv,
    const float* __restrict__ bgv, const float* __restrict__ bov,
    float* __restrict__ out)
{
    __shared__ unsigned char zs[131072];           // 128 rows x 512 k, bf16, frag order
    const int tid  = threadIdx.x;
    const int lane = tid & 63;
    const int wv   = tid >> 6;                     // 0..7
    const int l15  = lane & 15;
    const int lq   = lane >> 4;                    // 0..3
    const int row0 = blockIdx.x * 128;

    // ---- phase 0: z = x + stm -> bf16 -> LDS in frag order (verified layout) ----
    {
        const float* xb = xin + (size_t)row0 * 512;
        const float* sb = stm + (size_t)row0 * 512;
        #pragma unroll
        for (int it = 0; it < 16; ++it) {
            int idx = it * 512 + tid;              // [0, 8192): 128 rows x 64 kgroups
            int row = idx >> 6;
            int kg  = idx & 63;
            const float4* x4 = (const float4*)(xb + row * 512 + kg * 8);
            const float4* s4 = (const float4*)(sb + row * 512 + kg * 8);
            float4 a0 = x4[0], a1 = x4[1];
            float4 b0 = s4[0], b1 = s4[1];
            bf16x8 p;
            p[0] = (__bf16)(a0.x + b0.x); p[1] = (__bf16)(a0.y + b0.y);
            p[2] = (__bf16)(a0.z + b0.z); p[3] = (__bf16)(a0.w + b0.w);
            p[4] = (__bf16)(a1.x + b1.x); p[5] = (__bf16)(a1.y + b1.y);
            p[6] = (__bf16)(a1.z + b1.z); p[7] = (__bf16)(a1.w + b1.w);
            int rb   = row >> 5;                   // 0..3 chunk (32 KiB each)
            int kk   = kg >> 1;
            int slot = ((row & 31) + (kg & 1) * 32) ^ (kk & 7);
            *(bf16x8*)(zs + rb * 32768 + kk * 1024 + slot * 16) = p;
        }
    }
    __syncthreads();                               // only barrier

    // A-read invariants (verified r6 formulas):
    // byte = (m>>1)*32768 + (m&1)*256 + ((s0^kk7)<<4) + ks*2048 + (kkoff<<10)
    const int kkoff = lq >> 1;                     // 0/1
    const int s0    = l15 + (lq & 1) * 32;         // bit4 clear
    const int koffb = kkoff << 10;

#define LOADB(P, KS) { \
    const __bf16* p_ = bp + (KS) * 2048; \
    P##0 = *(const bf16x8*)(p_); \
    P##1 = *(const bf16x8*)(p_ + 512); \
    P##2 = *(const bf16x8*)(p_ + 1024); \
    P##3 = *(const bf16x8*)(p_ + 1536); }
#define DOMFMA(P, KS) { \
    const int kk7_ = ((2 * (KS)) & 7) | kkoff; \
    const int t0_  = ((s0 ^ kk7_) << 4) + (KS) * 2048 + koffb; \
    bf16x8 a_[8]; \
    _Pragma("unroll") \
    for (int m = 0; m < 8; ++m) \
        a_[m] = *(const bf16x8*)(zs + (m >> 1) * 32768 + (m & 1) * 256 + t0_); \
    _Pragma("unroll") \
    for (int m = 0; m < 8; ++m) { \
        acc[m][0] = __builtin_amdgcn_mfma_f32_16x16x32_bf16(a_[m], P##0, acc[m][0], 0, 0, 0); \
        acc[m][1] = __builtin_amdgcn_mfma_f32_16x16x32_bf16(a_[m], P##1, acc[m][1], 0, 0, 0); \
        acc[m][2] = __builtin_amdgcn_mfma_f32_16x16x32_bf16(a_[m], P##2, acc[m][2], 0, 0, 0); \
        acc[m][3] = __builtin_amdgcn_mfma_f32_16x16x32_bf16(a_[m], P##3, acc[m][3], 0, 0, 0); } }

    // ---- phase 1: column loop, no barriers ----
    for (int ci = 0; ci < 4; ++ci) {
        const int cn   = ci * 8 + wv;              // 16-col group [0,32)
        const int colj = cn * 16 + l15;

        const __bf16* bp = Wp + (size_t)cn * 32768 + lane * 8;  // gate-contig base

        float bias0 = bfv[colj], bias1 = biv[colj], bias2 = bgv[colj], bias3 = bov[colj];
        f32x4 acc[8][4];                           // [m][gate] = 128 AGPR
        #pragma unroll
        for (int m = 0; m < 8; ++m) {
            #pragma unroll
            for (int r = 0; r < 4; ++r) {
                acc[m][0][r] = bias0; acc[m][1][r] = bias1;
                acc[m][2][r] = bias2; acc[m][3][r] = bias3;
            }
        }

        bf16x8 bA0, bA1, bA2, bA3;                 // B set A
        bf16x8 bB0, bB1, bB2, bB3;                 // B set B

        LOADB(bA, 0)
        #pragma unroll
        for (int ks = 0; ks < 16; ks += 2) {
            LOADB(bB, ks + 1)                      // in flight under MFMA(ks)
            DOMFMA(bA, ks)
            if (ks + 2 < 16) LOADB(bA, ks + 2)     // in flight under MFMA(ks+1)
            DOMFMA(bB, ks + 1)
        }

        // ---- epilogue: 16x16 C/D layout col=l&15, row=lq*4+r ----
        #pragma unroll
        for (int m = 0; m < 8; ++m) {
            #pragma unroll
            for (int r = 0; r < 4; ++r) {
                float F = acc[m][0][r], I = acc[m][1][r];
                float G = acc[m][2][r], O = acc[m][3][r];
                float c = fsigmoid(F) + fsigmoid(I) * ftanh(G);
                float h = ftanh(c) * fsigmoid(O);
                int row = row0 + m * 16 + lq * 4 + r;
                int o   = row * 512 + colj;
                out[o] = c;
                out[33554432 + o] = h;             // h plane at 65536*512
            }
        }
    }
#undef LOADB
#undef DOMFMA
}

extern "C" void kernel_launch(void* const* d_in, const int* in_sizes, int n_in,
                              void* d_out, int out_size, void* d_ws, size_t ws_size,
                              hipStream_t stream) {
    const float* xin = (const float*)d_in[0];
    const float* stm = (const float*)d_in[1];
    const float* Wf  = (const float*)d_in[2];
    const float* bf_ = (const float*)d_in[3];
    const float* Wi  = (const float*)d_in[4];
    const float* bi_ = (const float*)d_in[5];
    const float* Wg  = (const float*)d_in[6];
    const float* bg_ = (const float*)d_in[7];
    const float* Wo  = (const float*)d_in[8];
    const float* bo_ = (const float*)d_in[9];
    __bf16* Wp = (__bf16*)d_ws;                    // 2 MiB packed weights

    wpack<<<512, 256, 0, stream>>>(Wf, Wi, Wg, Wo, Wp);
    lstm_main<<<512, 512, 0, stream>>>(xin, stm, Wp, bf_, bi_, bg_, bo_, (float*)d_out);
}

// Round 11
// 215.771 us; speedup vs baseline: 3.2805x; 3.2805x over previous
//
#include <hip/hip_runtime.h>

typedef __bf16 bf16x8 __attribute__((ext_vector_type(8)));
typedef float  f32x4  __attribute__((ext_vector_type(4)));

#define LOG2E 1.4426950408889634f

static __device__ __forceinline__ float fexp2(float x) { return __builtin_amdgcn_exp2f(x); }
static __device__ __forceinline__ float frcp(float x)  { return __builtin_amdgcn_rcpf(x); }
static __device__ __forceinline__ float fsigmoid(float x) { return frcp(1.0f + fexp2(-LOG2E * x)); }
static __device__ __forceinline__ float ftanh(float x)    { return 2.0f * frcp(1.0f + fexp2(-2.0f * LOG2E * x)) - 1.0f; }

// ---------------------------------------------------------------------------
// Prep (verified r10): pack 4 [512x512] fp32 weights into bf16 16x16x32
// B-fragment order, GATE-CONTIGUOUS:
// Wp[(((cn*16+ks)*4+g)*64 + lt)*8 + e] = W_g[cn*16+(lt&15)][ks*32+(lt>>4)*8+e]
// ---------------------------------------------------------------------------
__global__ __launch_bounds__(256) void wpack(const float* __restrict__ Wf,
                                             const float* __restrict__ Wi,
                                             const float* __restrict__ Wg,
                                             const float* __restrict__ Wo,
                                             __bf16* __restrict__ Wp)
{
    int idx = blockIdx.x * 256 + threadIdx.x;      // [0, 131072)
    int kg  = idx & 63;                            // k-group of 8
    int j   = (idx >> 6) & 511;                    // weight row = output col
    int g   = idx >> 15;
    const float* src = (g == 0) ? Wf : (g == 1) ? Wi : (g == 2) ? Wg : Wo;
    const float4* s4 = (const float4*)(src + j * 512 + kg * 8);
    float4 v0 = s4[0], v1 = s4[1];
    bf16x8 o;
    o[0] = (__bf16)v0.x; o[1] = (__bf16)v0.y; o[2] = (__bf16)v0.z; o[3] = (__bf16)v0.w;
    o[4] = (__bf16)v1.x; o[5] = (__bf16)v1.y; o[6] = (__bf16)v1.z; o[7] = (__bf16)v1.w;
    int cn = j >> 4;                               // 16-col group
    int ks = kg >> 2;                              // K=32 step
    int lt = (j & 15) + (kg & 3) * 16;             // lane slot
    size_t dst = ((size_t)(((cn * 16 + ks) * 4 + g) * 64 + lt)) * 8;
    *(bf16x8*)(Wp + dst) = o;
}

// ---------------------------------------------------------------------------
// Persistent main kernel. 256 blocks x 4 tiles (BM=64). 512 thr (8 waves),
// LDS = 2 x 64 KiB ping-pong z buffers. Wave owns all 64 rows x 16 cols x
// 4 gates (acc = 4m x 4g x 4 = 64 AGPR). While tile t computes from buf[cur],
// tile t+1 is staged into buf[nxt]: loads at ks=0/1, ds_writes at ks=8/9
// (HBM latency hidden under MFMA). One barrier per tile.
// ---------------------------------------------------------------------------
__global__ __launch_bounds__(512, 2) void lstm_main(
    const float* __restrict__ xin, const float* __restrict__ stm,
    const __bf16* __restrict__ Wp,
    const float* __restrict__ bfv, const float* __restrict__ biv,
    const float* __restrict__ bgv, const float* __restrict__ bov,
    float* __restrict__ out)
{
    __shared__ unsigned char zs[131072];           // two 64-KiB tile buffers
    const int tid  = threadIdx.x;
    const int lane = tid & 63;
    const int wv   = tid >> 6;                     // 0..7
    const int l15  = lane & 15;
    const int lq   = lane >> 4;                    // 0..3
    const int b    = blockIdx.x;                   // 0..255

    // A-read invariants (verified r5 formulas)
    const int kkoff = lq >> 1;                     // 0/1
    const int sl0   = l15 + (lq & 1) * 32;         // bit4 clear
    const int koffb = kkoff << 10;

    // staging invariants: wave stages row rnd*8+wv, lane covers kg=lane (8 k)
    const int st_kk   = lane >> 1;
    const int st_hi   = (lane & 1) << 5;
    const int st_xor  = st_kk & 7;
    const int st_base = st_kk << 10;               // chunk byte

#define STLOAD(X0, X1, S0, S1, RND, ROWB) { \
    const float* xp_ = xin + ((ROWB) + (RND) * 8 + wv) * 512 + lane * 8; \
    const float* sp_ = stm + ((ROWB) + (RND) * 8 + wv) * 512 + lane * 8; \
    X0 = *(const float4*)(xp_);     X1 = *(const float4*)(xp_ + 4); \
    S0 = *(const float4*)(sp_);     S1 = *(const float4*)(sp_ + 4); }

#define STWRITE(X0, X1, S0, S1, RND, BUF) { \
    bf16x8 p_; \
    p_[0] = (__bf16)(X0.x + S0.x); p_[1] = (__bf16)(X0.y + S0.y); \
    p_[2] = (__bf16)(X0.z + S0.z); p_[3] = (__bf16)(X0.w + S0.w); \
    p_[4] = (__bf16)(X1.x + S1.x); p_[5] = (__bf16)(X1.y + S1.y); \
    p_[6] = (__bf16)(X1.z + S1.z); p_[7] = (__bf16)(X1.w + S1.w); \
    int row_ = (RND) * 8 + wv; \
    int byte_ = ((row_ >> 5) << 15) | st_base | \
                (((((row_ & 31) + st_hi)) ^ st_xor) << 4); \
    *(bf16x8*)((BUF) + byte_) = p_; }

    unsigned char* bufc = zs;                      // compute buffer
    unsigned char* bufn = zs + 65536;              // staging buffer

    // ---- prologue: stage tile b into bufc ----
    {
        const size_t prow = (size_t)b * 64;
        #pragma unroll
        for (int rnd = 0; rnd < 8; ++rnd) {
            float4 x0, x1, s0v, s1v;
            STLOAD(x0, x1, s0v, s1v, rnd, prow)
            STWRITE(x0, x1, s0v, s1v, rnd, bufc)
        }
    }
    __syncthreads();

    for (int t = 0; t < 4; ++t) {
        const int tile = b + t * 256;
        const int row0 = tile * 64;
        const bool stg = (t < 3);
        const size_t nrow = (size_t)(tile + 256) * 64;

        for (int ci = 0; ci < 4; ++ci) {
            const int cn   = ci * 8 + wv;          // 16-col group [0,32)
            const int colj = cn * 16 + l15;
            const __bf16* bp = Wp + (size_t)cn * 32768 + lane * 8;

            float bias0 = bfv[colj], bias1 = biv[colj];
            float bias2 = bgv[colj], bias3 = bov[colj];
            f32x4 acc[4][4];                       // [m][gate] = 64 AGPR
            #pragma unroll
            for (int m = 0; m < 4; ++m) {
                #pragma unroll
                for (int r = 0; r < 4; ++r) {
                    acc[m][0][r] = bias0; acc[m][1][r] = bias1;
                    acc[m][2][r] = bias2; acc[m][3][r] = bias3;
                }
            }

            float4 ax0, ax1, as0, as1;             // staging set A (rnd = 2ci)
            float4 bx0, bx1, bs0, bs1;             // staging set B (rnd = 2ci+1)

            #pragma unroll
            for (int ks = 0; ks < 16; ++ks) {
                if (stg) {
                    if (ks == 0) STLOAD(ax0, ax1, as0, as1, 2 * ci,     nrow)
                    if (ks == 1) STLOAD(bx0, bx1, bs0, bs1, 2 * ci + 1, nrow)
                    if (ks == 8) STWRITE(ax0, ax1, as0, as1, 2 * ci,     bufn)
                    if (ks == 9) STWRITE(bx0, bx1, bs0, bs1, 2 * ci + 1, bufn)
                }
                const int kk7 = ((2 * ks) & 7) | kkoff;
                const int t0  = ((sl0 ^ kk7) << 4) + ks * 2048 + koffb;
                const __bf16* p_ = bp + ks * 2048;
                bf16x8 b0 = *(const bf16x8*)(p_);
                bf16x8 b1 = *(const bf16x8*)(p_ + 512);
                bf16x8 b2 = *(const bf16x8*)(p_ + 1024);
                bf16x8 b3 = *(const bf16x8*)(p_ + 1536);
                bf16x8 a[4];
                #pragma unroll
                for (int m = 0; m < 4; ++m)
                    a[m] = *(const bf16x8*)(bufc + (m >> 1) * 32768 + (m & 1) * 256 + t0);
                #pragma unroll
                for (int m = 0; m < 4; ++m) {
                    acc[m][0] = __builtin_amdgcn_mfma_f32_16x16x32_bf16(a[m], b0, acc[m][0], 0, 0, 0);
                    acc[m][1] = __builtin_amdgcn_mfma_f32_16x16x32_bf16(a[m], b1, acc[m][1], 0, 0, 0);
                    acc[m][2] = __builtin_amdgcn_mfma_f32_16x16x32_bf16(a[m], b2, acc[m][2], 0, 0, 0);
                    acc[m][3] = __builtin_amdgcn_mfma_f32_16x16x32_bf16(a[m], b3, acc[m][3], 0, 0, 0);
                }
            }

            // ---- epilogue (verified r5): col = l&15, row = lq*4 + r ----
            #pragma unroll
            for (int m = 0; m < 4; ++m) {
                #pragma unroll
                for (int r = 0; r < 4; ++r) {
                    float F = acc[m][0][r], I = acc[m][1][r];
                    float G = acc[m][2][r], O = acc[m][3][r];
                    float c = fsigmoid(F) + fsigmoid(I) * ftanh(G);
                    float h = ftanh(c) * fsigmoid(O);
                    int row = row0 + m * 16 + lq * 4 + r;
                    int o   = row * 512 + colj;
                    out[o] = c;
                    out[33554432 + o] = h;         // h plane at 65536*512
                }
            }
        }

        __syncthreads();                           // staging writes complete
        unsigned char* tmp = bufc; bufc = bufn; bufn = tmp;
    }
#undef STLOAD
#undef STWRITE
}

extern "C" void kernel_launch(void* const* d_in, const int* in_sizes, int n_in,
                              void* d_out, int out_size, void* d_ws, size_t ws_size,
                              hipStream_t stream) {
    const float* xin = (const float*)d_in[0];
    const float* stm = (const float*)d_in[1];
    const float* Wf  = (const float*)d_in[2];
    const float* bf_ = (const float*)d_in[3];
    const float* Wi  = (const float*)d_in[4];
    const float* bi_ = (const float*)d_in[5];
    const float* Wg  = (const float*)d_in[6];
    const float* bg_ = (const float*)d_in[7];
    const float* Wo  = (const float*)d_in[8];
    const float* bo_ = (const float*)d_in[9];
    __bf16* Wp = (__bf16*)d_ws;                    // 2 MiB packed weights

    wpack<<<512, 256, 0, stream>>>(Wf, Wi, Wg, Wo, Wp);
    lstm_main<<<256, 512, 0, stream>>>(xin, stm, Wp, bf_, bi_, bg_, bo_, (float*)d_out);
}

// Round 12
// 209.412 us; speedup vs baseline: 3.3801x; 1.0304x over previous
//
#include <hip/hip_runtime.h>

typedef __bf16 bf16x8 __attribute__((ext_vector_type(8)));
typedef float  f32x4  __attribute__((ext_vector_type(4)));

#define LOG2E 1.4426950408889634f

static __device__ __forceinline__ float fexp2(float x) { return __builtin_amdgcn_exp2f(x); }
static __device__ __forceinline__ float frcp(float x)  { return __builtin_amdgcn_rcpf(x); }
static __device__ __forceinline__ float fsigmoid(float x) { return frcp(1.0f + fexp2(-LOG2E * x)); }
static __device__ __forceinline__ float ftanh(float x)    { return 2.0f * frcp(1.0f + fexp2(-2.0f * LOG2E * x)) - 1.0f; }

// ---------------------------------------------------------------------------
// Prep (verified r10/r11): pack 4 [512x512] fp32 weights into bf16 16x16x32
// B-fragment order, GATE-CONTIGUOUS:
// Wp[(((cn*16+ks)*4+g)*64 + lt)*8 + e] = W_g[cn*16+(lt&15)][ks*32+(lt>>4)*8+e]
// ---------------------------------------------------------------------------
__global__ __launch_bounds__(256) void wpack(const float* __restrict__ Wf,
                                             const float* __restrict__ Wi,
                                             const float* __restrict__ Wg,
                                             const float* __restrict__ Wo,
                                             __bf16* __restrict__ Wp)
{
    int idx = blockIdx.x * 256 + threadIdx.x;      // [0, 131072)
    int kg  = idx & 63;                            // k-group of 8
    int j   = (idx >> 6) & 511;                    // weight row = output col
    int g   = idx >> 15;
    const float* src = (g == 0) ? Wf : (g == 1) ? Wi : (g == 2) ? Wg : Wo;
    const float4* s4 = (const float4*)(src + j * 512 + kg * 8);
    float4 v0 = s4[0], v1 = s4[1];
    bf16x8 o;
    o[0] = (__bf16)v0.x; o[1] = (__bf16)v0.y; o[2] = (__bf16)v0.z; o[3] = (__bf16)v0.w;
    o[4] = (__bf16)v1.x; o[5] = (__bf16)v1.y; o[6] = (__bf16)v1.z; o[7] = (__bf16)v1.w;
    int cn = j >> 4;                               // 16-col group
    int ks = kg >> 2;                              // K=32 step
    int lt = (j & 15) + (kg & 3) * 16;             // lane slot
    size_t dst = ((size_t)(((cn * 16 + ks) * 4 + g) * 64 + lt)) * 8;
    *(bf16x8*)(Wp + dst) = o;
}

// ---------------------------------------------------------------------------
// Persistent main kernel (r11 skeleton + 2-deep B register pipeline).
// 256 blocks x 4 tiles (BM=64). 512 thr (8 waves), LDS = 2 x 64 KiB ping-pong.
// Wave owns all 64 rows x 16 cols x 4 gates (acc = 64 AGPR).
// K-loop: B(ks+1) issued into the alternate register set BEFORE MFMA(ks), so
// B L2 latency hides under the previous MFMA batch instead of being exposed.
// ---------------------------------------------------------------------------
__global__ __launch_bounds__(512, 2) void lstm_main(
    const float* __restrict__ xin, const float* __restrict__ stm,
    const __bf16* __restrict__ Wp,
    const float* __restrict__ bfv, const float* __restrict__ biv,
    const float* __restrict__ bgv, const float* __restrict__ bov,
    float* __restrict__ out)
{
    __shared__ unsigned char zs[131072];           // two 64-KiB tile buffers
    const int tid  = threadIdx.x;
    const int lane = tid & 63;
    const int wv   = tid >> 6;                     // 0..7
    const int l15  = lane & 15;
    const int lq   = lane >> 4;                    // 0..3
    const int b    = blockIdx.x;                   // 0..255

    // A-read invariants (verified r5/r11 formulas)
    const int kkoff = lq >> 1;                     // 0/1
    const int sl0   = l15 + (lq & 1) * 32;         // bit4 clear
    const int koffb = kkoff << 10;

    // staging invariants: wave stages row rnd*8+wv, lane covers kg=lane (8 k)
    const int st_kk   = lane >> 1;
    const int st_hi   = (lane & 1) << 5;
    const int st_xor  = st_kk & 7;
    const int st_base = st_kk << 10;               // chunk byte

#define STLOAD(X0, X1, S0, S1, RND, ROWB) { \
    const float* xp_ = xin + ((ROWB) + (RND) * 8 + wv) * 512 + lane * 8; \
    const float* sp_ = stm + ((ROWB) + (RND) * 8 + wv) * 512 + lane * 8; \
    X0 = *(const float4*)(xp_);     X1 = *(const float4*)(xp_ + 4); \
    S0 = *(const float4*)(sp_);     S1 = *(const float4*)(sp_ + 4); }

#define STWRITE(X0, X1, S0, S1, RND, BUF) { \
    bf16x8 p_; \
    p_[0] = (__bf16)(X0.x + S0.x); p_[1] = (__bf16)(X0.y + S0.y); \
    p_[2] = (__bf16)(X0.z + S0.z); p_[3] = (__bf16)(X0.w + S0.w); \
    p_[4] = (__bf16)(X1.x + S1.x); p_[5] = (__bf16)(X1.y + S1.y); \
    p_[6] = (__bf16)(X1.z + S1.z); p_[7] = (__bf16)(X1.w + S1.w); \
    int row_ = (RND) * 8 + wv; \
    int byte_ = ((row_ >> 5) << 15) | st_base | \
                (((((row_ & 31) + st_hi)) ^ st_xor) << 4); \
    *(bf16x8*)((BUF) + byte_) = p_; }

#define LOADB(P, KS) { \
    const __bf16* p_ = bp + (KS) * 2048; \
    P##0 = *(const bf16x8*)(p_); \
    P##1 = *(const bf16x8*)(p_ + 512); \
    P##2 = *(const bf16x8*)(p_ + 1024); \
    P##3 = *(const bf16x8*)(p_ + 1536); }

#define DOMFMA(P, KS) { \
    const int kk7_ = ((2 * (KS)) & 7) | kkoff; \
    const int t0_  = ((sl0 ^ kk7_) << 4) + (KS) * 2048 + koffb; \
    bf16x8 a_[4]; \
    _Pragma("unroll") \
    for (int m = 0; m < 4; ++m) \
        a_[m] = *(const bf16x8*)(bufc + (m >> 1) * 32768 + (m & 1) * 256 + t0_); \
    _Pragma("unroll") \
    for (int m = 0; m < 4; ++m) { \
        acc[m][0] = __builtin_amdgcn_mfma_f32_16x16x32_bf16(a_[m], P##0, acc[m][0], 0, 0, 0); \
        acc[m][1] = __builtin_amdgcn_mfma_f32_16x16x32_bf16(a_[m], P##1, acc[m][1], 0, 0, 0); \
        acc[m][2] = __builtin_amdgcn_mfma_f32_16x16x32_bf16(a_[m], P##2, acc[m][2], 0, 0, 0); \
        acc[m][3] = __builtin_amdgcn_mfma_f32_16x16x32_bf16(a_[m], P##3, acc[m][3], 0, 0, 0); } }

    unsigned char* bufc = zs;                      // compute buffer
    unsigned char* bufn = zs + 65536;              // staging buffer

    // ---- prologue: stage tile b into bufc ----
    {
        const size_t prow = (size_t)b * 64;
        #pragma unroll
        for (int rnd = 0; rnd < 8; ++rnd) {
            float4 x0, x1, s0v, s1v;
            STLOAD(x0, x1, s0v, s1v, rnd, prow)
            STWRITE(x0, x1, s0v, s1v, rnd, bufc)
        }
    }
    __syncthreads();

    for (int t = 0; t < 4; ++t) {
        const int tile = b + t * 256;
        const int row0 = tile * 64;
        const bool stg = (t < 3);
        const size_t nrow = (size_t)(tile + 256) * 64;

        for (int ci = 0; ci < 4; ++ci) {
            const int cn   = ci * 8 + wv;          // 16-col group [0,32)
            const int colj = cn * 16 + l15;
            const __bf16* bp = Wp + (size_t)cn * 32768 + lane * 8;

            float bias0 = bfv[colj], bias1 = biv[colj];
            float bias2 = bgv[colj], bias3 = bov[colj];
            f32x4 acc[4][4];                       // [m][gate] = 64 AGPR
            #pragma unroll
            for (int m = 0; m < 4; ++m) {
                #pragma unroll
                for (int r = 0; r < 4; ++r) {
                    acc[m][0][r] = bias0; acc[m][1][r] = bias1;
                    acc[m][2][r] = bias2; acc[m][3][r] = bias3;
                }
            }

            float4 ax0, ax1, as0, as1;             // staging set A (rnd = 2ci)
            float4 bx0, bx1, bs0, bs1;             // staging set B (rnd = 2ci+1)
            bf16x8 bA0, bA1, bA2, bA3;             // B pipeline set A
            bf16x8 bB0, bB1, bB2, bB3;             // B pipeline set B

            LOADB(bA, 0)
            #pragma unroll
            for (int ks = 0; ks < 16; ks += 2) {
                if (stg && ks == 0) STLOAD(ax0, ax1, as0, as1, 2 * ci, nrow)
                LOADB(bB, ks + 1)                  // in flight under MFMA(ks)
                DOMFMA(bA, ks)
                if (stg && ks == 0) STLOAD(bx0, bx1, bs0, bs1, 2 * ci + 1, nrow)
                if (stg && ks == 8) STWRITE(ax0, ax1, as0, as1, 2 * ci, bufn)
                if (ks + 2 < 16) LOADB(bA, ks + 2) // in flight under MFMA(ks+1)
                DOMFMA(bB, ks + 1)
                if (stg && ks == 8) STWRITE(bx0, bx1, bs0, bs1, 2 * ci + 1, bufn)
            }

            // ---- epilogue (verified r5/r11): col = l&15, row = lq*4 + r ----
            #pragma unroll
            for (int m = 0; m < 4; ++m) {
                #pragma unroll
                for (int r = 0; r < 4; ++r) {
                    float F = acc[m][0][r], I = acc[m][1][r];
                    float G = acc[m][2][r], O = acc[m][3][r];
                    float c = fsigmoid(F) + fsigmoid(I) * ftanh(G);
                    float h = ftanh(c) * fsigmoid(O);
                    int row = row0 + m * 16 + lq * 4 + r;
                    int o   = row * 512 + colj;
                    out[o] = c;
                    out[33554432 + o] = h;         // h plane at 65536*512
                }
            }
        }

        __syncthreads();                           // staging writes complete
        unsigned char* tmp = bufc; bufc = bufn; bufn = tmp;
    }
#undef STLOAD
#undef STWRITE
#undef LOADB
#undef DOMFMA
}

extern "C" void kernel_launch(void* const* d_in, const int* in_sizes, int n_in,
                              void* d_out, int out_size, void* d_ws, size_t ws_size,
                              hipStream_t stream) {
    const float* xin = (const float*)d_in[0];
    const float* stm = (const float*)d_in[1];
    const float* Wf  = (const float*)d_in[2];
    const float* bf_ = (const float*)d_in[3];
    const float* Wi  = (const float*)d_in[4];
    const float* bi_ = (const float*)d_in[5];
    const float* Wg  = (const float*)d_in[6];
    const float* bg_ = (const float*)d_in[7];
    const float* Wo  = (const float*)d_in[8];
    const float* bo_ = (const float*)d_in[9];
    __bf16* Wp = (__bf16*)d_ws;                    // 2 MiB packed weights

    wpack<<<512, 256, 0, stream>>>(Wf, Wi, Wg, Wo, Wp);
    lstm_main<<<256, 512, 0, stream>>>(xin, stm, Wp, bf_, bi_, bg_, bo_, (float*)d_out);
}

// Round 13
// 190.446 us; speedup vs baseline: 3.7167x; 1.0996x over previous
//
#include <hip/hip_runtime.h>

typedef __bf16 bf16x8 __attribute__((ext_vector_type(8)));
typedef float  f32x4  __attribute__((ext_vector_type(4)));

#define LOG2E 1.4426950408889634f

static __device__ __forceinline__ float fexp2(float x) { return __builtin_amdgcn_exp2f(x); }
static __device__ __forceinline__ float frcp(float x)  { return __builtin_amdgcn_rcpf(x); }
static __device__ __forceinline__ float fsigmoid(float x) { return frcp(1.0f + fexp2(-LOG2E * x)); }
static __device__ __forceinline__ float ftanh(float x)    { return 2.0f * frcp(1.0f + fexp2(-2.0f * LOG2E * x)) - 1.0f; }

// ---------------------------------------------------------------------------
// Prep (verified r10-r12): pack 4 [512x512] fp32 weights into bf16 16x16x32
// B-fragment order, GATE-CONTIGUOUS:
// Wp[(((cn*16+ks)*4+g)*64 + lt)*8 + e] = W_g[cn*16+(lt&15)][ks*32+(lt>>4)*8+e]
// Per cn: 64 KiB; per (cn,ks): 4 KiB (4 gates x 1 KiB, lane-linear).
// ---------------------------------------------------------------------------
__global__ __launch_bounds__(256) void wpack(const float* __restrict__ Wf,
                                             const float* __restrict__ Wi,
                                             const float* __restrict__ Wg,
                                             const float* __restrict__ Wo,
                                             __bf16* __restrict__ Wp)
{
    int idx = blockIdx.x * 256 + threadIdx.x;      // [0, 131072)
    int kg  = idx & 63;                            // k-group of 8
    int j   = (idx >> 6) & 511;                    // weight row = output col
    int g   = idx >> 15;
    const float* src = (g == 0) ? Wf : (g == 1) ? Wi : (g == 2) ? Wg : Wo;
    const float4* s4 = (const float4*)(src + j * 512 + kg * 8);
    float4 v0 = s4[0], v1 = s4[1];
    bf16x8 o;
    o[0] = (__bf16)v0.x; o[1] = (__bf16)v0.y; o[2] = (__bf16)v0.z; o[3] = (__bf16)v0.w;
    o[4] = (__bf16)v1.x; o[5] = (__bf16)v1.y; o[6] = (__bf16)v1.z; o[7] = (__bf16)v1.w;
    int cn = j >> 4;                               // 16-col group
    int ks = kg >> 2;                              // K=32 step
    int lt = (j & 15) + (kg & 3) * 16;             // lane slot
    size_t dst = ((size_t)(((cn * 16 + ks) * 4 + g) * 64 + lt)) * 8;
    *(bf16x8*)(Wp + dst) = o;
}

// ---------------------------------------------------------------------------
// Main fused kernel = r6 skeleton + explicit B DMA pipeline (T3+T4 pattern).
// Block: 512 thr (8 waves), BM=128, LDS = 128K z-image + 8x4K B dbuf = 160 KiB.
// Per ks, two gate-pair chunks; each chunk: issue NEXT chunk's 2
// global_load_lds, s_waitcnt vmcnt(2) (counted - next stays in flight),
// sched_barrier, ds_read B, 16 MFMA. Compiler cannot sink the DMA or hoist
// the reads: the builtin is side-effecting and the asm has a memory clobber.
// ---------------------------------------------------------------------------
__global__ __launch_bounds__(512, 2) void lstm_main(
    const float* __restrict__ xin, const float* __restrict__ stm,
    const __bf16* __restrict__ Wp,
    const float* __restrict__ bfv, const float* __restrict__ biv,
    const float* __restrict__ bgv, const float* __restrict__ bov,
    float* __restrict__ out)
{
    __shared__ unsigned char lds[163840];          // 128K z + 32K B stage
    unsigned char* zs = lds;
    const int tid  = threadIdx.x;
    const int lane = tid & 63;
    const int wv   = tid >> 6;                     // 0..7
    const int l15  = lane & 15;
    const int lq   = lane >> 4;                    // 0..3
    const int row0 = blockIdx.x * 128;

    // ---- phase 0: z = x + stm -> bf16 -> LDS in frag order (verified r6) ----
    {
        const float* xb = xin + (size_t)row0 * 512;
        const float* sb = stm + (size_t)row0 * 512;
        #pragma unroll
        for (int it = 0; it < 16; ++it) {
            int idx = it * 512 + tid;              // [0, 8192): 128 rows x 64 kgroups
            int row = idx >> 6;
            int kg  = idx & 63;
            const float4* x4 = (const float4*)(xb + row * 512 + kg * 8);
            const float4* s4 = (const float4*)(sb + row * 512 + kg * 8);
            float4 a0 = x4[0], a1 = x4[1];
            float4 b0 = s4[0], b1 = s4[1];
            bf16x8 p;
            p[0] = (__bf16)(a0.x + b0.x); p[1] = (__bf16)(a0.y + b0.y);
            p[2] = (__bf16)(a0.z + b0.z); p[3] = (__bf16)(a0.w + b0.w);
            p[4] = (__bf16)(a1.x + b1.x); p[5] = (__bf16)(a1.y + b1.y);
            p[6] = (__bf16)(a1.z + b1.z); p[7] = (__bf16)(a1.w + b1.w);
            int rb   = row >> 5;                   // 0..3 chunk (32 KiB each)
            int kk   = kg >> 1;
            int slot = ((row & 31) + (kg & 1) * 32) ^ (kk & 7);
            *(bf16x8*)(zs + rb * 32768 + kk * 1024 + slot * 16) = p;
        }
    }
    __syncthreads();                               // only barrier

    // A-read invariants (verified r6):
    const int kkoff = lq >> 1;                     // 0/1
    const int sl0   = l15 + (lq & 1) * 32;         // bit4 clear
    const int koffb = kkoff << 10;

    unsigned char* bsw  = lds + 131072 + wv * 4096;   // wave's B stage (uniform)
    unsigned char* bswl = bsw + lane * 16;            // lane's read address

#define AS1(p) ((const __attribute__((address_space(1))) void*)(p))
#define AS3(p) ((__attribute__((address_space(3))) void*)(p))
#define ISSUE(IDX) { \
    const char* s_ = wpB + (IDX) * 2048 + lane * 16; \
    unsigned char* d_ = bsw + ((IDX) & 1) * 2048; \
    __builtin_amdgcn_global_load_lds(AS1(s_), AS3(d_), 16, 0, 0); \
    __builtin_amdgcn_global_load_lds(AS1(s_ + 1024), AS3(d_ + 1024), 16, 0, 0); }
#define WAITV2 { asm volatile("s_waitcnt vmcnt(2)" ::: "memory"); __builtin_amdgcn_sched_barrier(0); }
#define WAITV0 { asm volatile("s_waitcnt vmcnt(0)" ::: "memory"); __builtin_amdgcn_sched_barrier(0); }

    // ---- phase 1: column loop, no barriers ----
    for (int ci = 0; ci < 4; ++ci) {
        const int cn   = ci * 8 + wv;              // 16-col group [0,32)
        const int colj = cn * 16 + l15;
        const char* wpB = (const char*)Wp + (size_t)cn * 65536;

        float bias0 = bfv[colj], bias1 = biv[colj];
        float bias2 = bgv[colj], bias3 = bov[colj];
        f32x4 acc[8][4];                           // [m][gate] = 128 AGPR
        #pragma unroll
        for (int m = 0; m < 8; ++m) {
            #pragma unroll
            for (int r = 0; r < 4; ++r) {
                acc[m][0][r] = bias0; acc[m][1][r] = bias1;
                acc[m][2][r] = bias2; acc[m][3][r] = bias3;
            }
        }

        ISSUE(0)                                   // prime chunk 0 (gates 0,1)
        #pragma unroll
        for (int ks = 0; ks < 16; ++ks) {
            // ---- chunk 0: gates 0,1 from buffer 0 ----
            ISSUE(2 * ks + 1)                      // next: gates 2,3 -> buffer 1
            WAITV2
            bf16x8 a_[8];
            {
                const int kk7 = ((2 * ks) & 7) | kkoff;
                const int t0  = ((sl0 ^ kk7) << 4) + ks * 2048 + koffb;
                #pragma unroll
                for (int m = 0; m < 8; ++m)
                    a_[m] = *(const bf16x8*)(zs + (m >> 1) * 32768 + (m & 1) * 256 + t0);
            }
            {
                bf16x8 b0 = *(const bf16x8*)(bswl);
                bf16x8 b1 = *(const bf16x8*)(bswl + 1024);
                __builtin_amdgcn_s_setprio(1);
                #pragma unroll
                for (int m = 0; m < 8; ++m) {
                    acc[m][0] = __builtin_amdgcn_mfma_f32_16x16x32_bf16(a_[m], b0, acc[m][0], 0, 0, 0);
                    acc[m][1] = __builtin_amdgcn_mfma_f32_16x16x32_bf16(a_[m], b1, acc[m][1], 0, 0, 0);
                }
                __builtin_amdgcn_s_setprio(0);
            }
            // ---- chunk 1: gates 2,3 from buffer 1 ----
            if (ks < 15) { ISSUE(2 * ks + 2) WAITV2 }   // next ks chunk 0
            else         { WAITV0 }
            {
                bf16x8 b2 = *(const bf16x8*)(bswl + 2048);
                bf16x8 b3 = *(const bf16x8*)(bswl + 3072);
                __builtin_amdgcn_s_setprio(1);
                #pragma unroll
                for (int m = 0; m < 8; ++m) {
                    acc[m][2] = __builtin_amdgcn_mfma_f32_16x16x32_bf16(a_[m], b2, acc[m][2], 0, 0, 0);
                    acc[m][3] = __builtin_amdgcn_mfma_f32_16x16x32_bf16(a_[m], b3, acc[m][3], 0, 0, 0);
                }
                __builtin_amdgcn_s_setprio(0);
            }
        }

        // ---- epilogue (verified r6): col = l&15, row = lq*4 + r ----
        #pragma unroll
        for (int m = 0; m < 8; ++m) {
            #pragma unroll
            for (int r = 0; r < 4; ++r) {
                float F = acc[m][0][r], I = acc[m][1][r];
                float G = acc[m][2][r], O = acc[m][3][r];
                float c = fsigmoid(F) + fsigmoid(I) * ftanh(G);
                float h = ftanh(c) * fsigmoid(O);
                int row = row0 + m * 16 + lq * 4 + r;
                int o   = row * 512 + colj;
                out[o] = c;
                out[33554432 + o] = h;             // h plane at 65536*512
            }
        }
    }
#undef ISSUE
#undef WAITV2
#undef WAITV0
#undef AS1
#undef AS3
}

extern "C" void kernel_launch(void* const* d_in, const int* in_sizes, int n_in,
                              void* d_out, int out_size, void* d_ws, size_t ws_size,
                              hipStream_t stream) {
    const float* xin = (const float*)d_in[0];
    const float* stm = (const float*)d_in[1];
    const float* Wf  = (const float*)d_in[2];
    const float* bf_ = (const float*)d_in[3];
    const float* Wi  = (const float*)d_in[4];
    const float* bi_ = (const float*)d_in[5];
    const float* Wg  = (const float*)d_in[6];
    const float* bg_ = (const float*)d_in[7];
    const float* Wo  = (const float*)d_in[8];
    const float* bo_ = (const float*)d_in[9];
    __bf16* Wp = (__bf16*)d_ws;                    // 2 MiB packed weights

    wpack<<<512, 256, 0, stream>>>(Wf, Wi, Wg, Wo, Wp);
    lstm_main<<<512, 512, 0, stream>>>(xin, stm, Wp, bf_, bi_, bg_, bo_, (float*)d_out);
}